// Round 6
// baseline (448.149 us; speedup 1.0000x reference)
//
#include <hip/hip_runtime.h>
#include <stdint.h>

// Problem constants (reference: M,K,N = 8192,4096,4096)
#define M_DIM 8192
#define K_DIM 4096
#define N_DIM 4096

typedef __attribute__((ext_vector_type(4))) int v4i;

// ---------------------------------------------------------------------------
// Phase 1: pack int32 (harness-normalized int8 values in [-127,127]) -> int8.
// One thread = one v4i load (16 B/lane) + one dword store. Known-good.
// ---------------------------------------------------------------------------
__device__ __forceinline__ int pack4(v4i v) {
    return (int)(((uint32_t)v.x & 0xffu)
               | (((uint32_t)v.y & 0xffu) << 8)
               | (((uint32_t)v.z & 0xffu) << 16)
               | (((uint32_t)v.w & 0xffu) << 24));
}

__global__ __launch_bounds__(256) void pack_ab(
    const int* __restrict__ srcA, const int* __restrict__ srcB,
    int* __restrict__ dstA, int* __restrict__ dstB,
    int aGroups)
{
    int g = blockIdx.x * 256 + threadIdx.x;
    const v4i* src;
    int* dst;
    if (g < aGroups) { src = (const v4i*)srcA; dst = dstA; }
    else             { src = (const v4i*)srcB; dst = dstB; g -= aGroups; }
    dst[g] = pack4(src[g]);
}

// ---------------------------------------------------------------------------
// Async global->LDS, 16B per lane. LDS dest = wave-uniform base + lane*16
// (m104/m108); swizzled layouts realized by pre-swizzling the GLOBAL source.
// ---------------------------------------------------------------------------
__device__ __forceinline__ void gload16(const void* g, void* lds_p) {
    __builtin_amdgcn_global_load_lds(
        (__attribute__((address_space(1))) void*)(g),
        (__attribute__((address_space(3))) void*)(lds_p),
        16, 0, 0);
}

// ---------------------------------------------------------------------------
// Phase 2, ROUND 6 (= R5 resubmit; R5 bench was an infra failure, audit
// found no kernel fault): 128x128 tile, BK=128, 4 waves (2M x 2N), 64 KB
// LDS -> 2 blocks/CU. mfma_i32_16x16x64_i8 (R4's 32x32 was 4-way bank
// conflicted: 32-row b128 reads can only hit 8 bank-groups -> structural).
//
// Mechanism: R2/R3/R4 all measured phase wall ~1333 cyc = MFMA 650 +
// LDS-drain 580 SERIAL; at 1 block/CU (128 KB LDS) there is no co-resident
// work to cover the drains. Halving tile+LDS gives 2 independent blocks/CU
// (independent barriers): block Y issues MFMAs while block X drains
// (m97/m114 implicit wave-level overlap).
//
// Schedule = the VERIFIED R2 schedule mapped 1:1 (same 8-phase rhythm, same
// STAGE->read barrier distances, same vmcnt(4) flight accounting, same
// conflict-free 16-row reads; absmax 2.4e-4 in R1-R3):
//   regions: 2buf x {A,B} x {ks-half}, each 128 rows x 64 B = 8 KB (64 KB).
//   swizzle: slot (row,sc) holds k-granule cg = sc ^ ((row>>1)&3).
//   staging: thread t owns slots t and t+256 (rows t>>2 and t>>2+64); scg
//            identical for both slots ((t>>3)+32 preserves &3).
//   phases: p1..p8 cover K-tiles T(buf0), T+1(buf1); per phase: 2 A-frag +
//           (4 B-frag on qm0, reused qm1) reads, 8 MFMA, 1 STAGE.
//   stage->last-read distance 2 phases (>=1 barrier before stage issue).
//   vmcnt: WAIT4 at p4 (certifies buf1: prev p7,p8 + p1,p2) and p8
//          (certifies buf0: p3,p4 + p5,p6). Never vmcnt(0) in main loop.
// ---------------------------------------------------------------------------
__global__ __launch_bounds__(256, 2) void int8_gemm_dequant(
    const int8_t* __restrict__ A,        // [M,K] int8 packed
    const float*  __restrict__ scale_x,  // [M]
    const int8_t* __restrict__ W,        // [N,K] int8 packed
    const float*  __restrict__ scale_w,  // [N]
    const float*  __restrict__ bias,     // [N] (harness-normalized fp16->f32)
    float*        __restrict__ out)      // [M,N] f32
{
    __shared__ __align__(16) int8_t lds[65536];   // 64 KiB -> 2 blocks/CU

    const int t    = threadIdx.x;          // 0..255
    const int lane = t & 63;
    const int w    = t >> 6;               // wave 0..3
    const int wm   = w >> 1;               // 0..1  (M half: 64 rows)
    const int wn   = w & 1;                // 0..1  (N half: 64 cols)

    // Bijective XCD swizzle (2048 % 8 == 0): each XCD gets 256 consecutive
    // tiles = 8 full tile-rows of 32 -> A-panel reuse in its private L2.
    const int wg  = blockIdx.x;
    const int swz = (wg & 7) * 256 + (wg >> 3);
    const int n0  = (swz & 31) * 128;
    const int m0  = (swz >> 5) * 128;

    // Staging: thread t owns slots t and t+256 of each 8 KB region.
    // slot s -> row = s>>2, sc = s&3, global k-granule cg = sc ^ ((s>>3)&3).
    const int srow = t >> 2;                        // 0..63 (2nd slot: +64)
    const int scg  = (t & 3) ^ ((t >> 3) & 3);      // same for slot t+256
    const int8_t* Ap = A + (size_t)(m0 + srow) * K_DIM + scg * 16;
    const int8_t* Bp = W + (size_t)(n0 + srow) * K_DIM + scg * 16;
    int8_t* ldsb = &lds[t * 16];

    // Fragment read: lane reads row (base + (lane&15)), k-granule cg=lane>>4;
    // swizzled col = cg ^ ((lane>>1)&3) (all base rows are multiples of 16).
    const int rd = (lane & 15) * 64 + (((lane >> 4) ^ ((lane >> 1) & 3)) * 16);

    v4i acc[4][4] = {};                    // [qm*2+mt][nt]; row block = ii*16
    v4i afr[2], bfr[4];

#define HOFF(buf, mat, ksh) ((((buf) << 2) | ((mat) << 1) | (ksh)) << 13)

#define STAGE(buf, mat, ksh, OFF) do {                                        \
    const int8_t* _g = ((mat) ? Bp : Ap) + (OFF) + (ksh) * 64;                \
    int8_t* _d = ldsb + HOFF(buf, mat, ksh);                                  \
    gload16(_g, _d);                                                          \
    gload16(_g + (size_t)64 * K_DIM, _d + 4096);                              \
} while (0)

#define READ_B(buf, ksh) do {                                                 \
    const int8_t* _p = lds + HOFF(buf, 1, ksh) + wn * 4096 + rd;              \
    bfr[0] = *(const v4i*)(_p);                                               \
    bfr[1] = *(const v4i*)(_p + 1024);                                        \
    bfr[2] = *(const v4i*)(_p + 2048);                                        \
    bfr[3] = *(const v4i*)(_p + 3072);                                        \
} while (0)

#define READ_A(buf, ksh, qm) do {                                             \
    const int8_t* _p = lds + HOFF(buf, 0, ksh) + wm * 4096 + (qm) * 2048 + rd;\
    afr[0] = *(const v4i*)(_p);                                               \
    afr[1] = *(const v4i*)(_p + 1024);                                        \
} while (0)

#define MFMA_Q(qm) do {                                                       \
    _Pragma("unroll")                                                         \
    for (int mt = 0; mt < 2; ++mt) {                                          \
        _Pragma("unroll")                                                     \
        for (int nt = 0; nt < 4; ++nt) {                                      \
            acc[(qm) * 2 + mt][nt] = __builtin_amdgcn_mfma_i32_16x16x64_i8(   \
                afr[mt], bfr[nt], acc[(qm) * 2 + mt][nt], 0, 0, 0);           \
        }                                                                     \
    }                                                                         \
} while (0)

#define NOWAIT ((void)0)
#define WAIT4  asm volatile("s_waitcnt vmcnt(4)" ::: "memory")
#define WAIT0  asm volatile("s_waitcnt vmcnt(0)" ::: "memory")
#define NOSTG  ((void)0)

// R2's verified phase: reads -> stage -> [counted vmcnt] -> barrier ->
// lgkmcnt(0) -> MFMA. Inter-block concurrency (2 blocks/CU) provides the
// overlap that intra-block pipelining (R3) could not.
#define PHASE(DO_RB, buf, ksh, qm, STG, WAITV) do {                           \
    if (DO_RB) { READ_B(buf, ksh); }                                          \
    READ_A(buf, ksh, qm);                                                     \
    STG;                                                                      \
    WAITV;                                                                    \
    __builtin_amdgcn_s_barrier();                                             \
    asm volatile("s_waitcnt lgkmcnt(0)" ::: "memory");                        \
    __builtin_amdgcn_s_setprio(1);                                            \
    MFMA_Q(qm);                                                               \
    __builtin_amdgcn_s_setprio(0);                                            \
} while (0)

    // Prologue: tile0 full (8 loads) + tile1 ks0 (4 loads); drain tile0,
    // leave tile1.ks0's 4 in flight (steady-state entry condition).
    STAGE(0, 1, 0, 0);   STAGE(0, 0, 0, 0);
    STAGE(0, 1, 1, 0);   STAGE(0, 0, 1, 0);
    STAGE(1, 1, 0, 128); STAGE(1, 0, 0, 128);
    WAIT4;
    __builtin_amdgcn_s_barrier();

    // Main loop: i = 0..14; Ap/Bp advance 256 B/iter so stage offsets are
    // immediates: T1 = +128, T2 = +256, T3 = +384 (ksh adds 64).
    for (int i = 0; i < 15; ++i) {
        PHASE(1, 0, 0, 0, STAGE(1, 1, 1, 128), NOWAIT);   // p1
        PHASE(0, 0, 0, 1, STAGE(1, 0, 1, 128), NOWAIT);   // p2
        PHASE(1, 0, 1, 0, STAGE(0, 1, 0, 256), NOWAIT);   // p3
        PHASE(0, 0, 1, 1, STAGE(0, 0, 0, 256), WAIT4);    // p4
        PHASE(1, 1, 0, 0, STAGE(0, 1, 1, 256), NOWAIT);   // p5
        PHASE(0, 1, 0, 1, STAGE(0, 0, 1, 256), NOWAIT);   // p6
        PHASE(1, 1, 1, 0, STAGE(1, 1, 0, 384), NOWAIT);   // p7
        PHASE(0, 1, 1, 1, STAGE(1, 0, 0, 384), WAIT4);    // p8
        Ap += 256; Bp += 256;
    }

    // Peeled final iteration (tiles 30,31): finish staging tile31.ks1, then
    // drain everything once (outside steady state) and compute.
    PHASE(1, 0, 0, 0, STAGE(1, 1, 1, 128), NOWAIT);
    PHASE(0, 0, 0, 1, STAGE(1, 0, 1, 128), NOWAIT);
    PHASE(1, 0, 1, 0, NOSTG, NOWAIT);
    PHASE(0, 0, 1, 1, NOSTG, WAIT0);
    PHASE(1, 1, 0, 0, NOSTG, NOWAIT);
    PHASE(0, 1, 0, 1, NOSTG, NOWAIT);
    PHASE(1, 1, 1, 0, NOSTG, NOWAIT);
    PHASE(0, 1, 1, 1, NOSTG, NOWAIT);

    // Epilogue: dequant + bias. C/D layout (16x16, dtype-independent):
    // col = lane&15, row = (lane>>4)*4 + reg. acc[ii] covers rows ii*16.
    const int col = lane & 15;
    const int rq  = (lane >> 4) * 4;
    const float inv127sq = 1.0f / (127.0f * 127.0f);
    const int mbase = m0 + wm * 64;
    const int nbase = n0 + wn * 64;

    float sx[4][4];
#pragma unroll
    for (int ii = 0; ii < 4; ++ii) {
        const int mrow = mbase + ii * 16 + rq;
#pragma unroll
        for (int r = 0; r < 4; ++r) sx[ii][r] = scale_x[mrow + r];
    }

#pragma unroll
    for (int j = 0; j < 4; ++j) {
        const int n  = nbase + j * 16 + col;
        const float sw = scale_w[n] * inv127sq;
        const float bf = bias[n];
#pragma unroll
        for (int ii = 0; ii < 4; ++ii) {
            const int mrow = mbase + ii * 16 + rq;
#pragma unroll
            for (int r = 0; r < 4; ++r) {
                out[(size_t)(mrow + r) * N_DIM + n] =
                    (float)acc[ii][j][r] * sx[ii][r] * sw + bf;
            }
        }
    }

#undef HOFF
#undef STAGE
#undef READ_B
#undef READ_A
#undef MFMA_Q
#undef NOWAIT
#undef WAIT4
#undef WAIT0
#undef NOSTG
#undef PHASE
}

extern "C" void kernel_launch(void* const* d_in, const int* in_sizes, int n_in,
                              void* d_out, int out_size, void* d_ws, size_t ws_size,
                              hipStream_t stream) {
    // Harness normalization: integer inputs -> int32, fp16 -> f32.
    const int*   x_i32   = (const int*)  d_in[0];   // [M,K] as int32
    const float* scale_x = (const float*)d_in[1];   // [M] f32
    const int*   w_i32   = (const int*)  d_in[2];   // [N,K] as int32
    const float* scale_w = (const float*)d_in[3];   // [N] f32
    const float* bias    = (const float*)d_in[4];   // [N] f32 (from fp16)
    float* out = (float*)d_out;                     // [M,N] f32

    // Scratch layout: packed A8 then B8.
    int8_t* A8 = (int8_t*)d_ws;                          // 33,554,432 B
    int8_t* B8 = A8 + (size_t)M_DIM * K_DIM;             // 16,777,216 B

    const int a_groups = (M_DIM * K_DIM) / 4;            // 8,388,608
    const int b_groups = (N_DIM * K_DIM) / 4;            // 4,194,304
    const int total    = a_groups + b_groups;            // 12,582,912 (÷256)
    pack_ab<<<total / 256, 256, 0, stream>>>(x_i32, w_i32, (int*)A8, (int*)B8,
                                             a_groups);

    // 128x128 tiles: grid = (8192/128)*(4096/128) = 64*32 = 2048 blocks,
    // 256 threads, 64 KB LDS -> 2 blocks/CU.
    int8_gemm_dequant<<<2048, 256, 0, stream>>>(A8, scale_x, B8, scale_w, bias, out);
}

// Round 7
// 393.507 us; speedup vs baseline: 1.1389x; 1.1389x over previous
//
#include <hip/hip_runtime.h>
#include <stdint.h>

// Problem constants (reference: M,K,N = 8192,4096,4096)
#define M_DIM 8192
#define K_DIM 4096
#define N_DIM 4096

typedef __attribute__((ext_vector_type(4))) int v4i;

// ---------------------------------------------------------------------------
// Phase 1: pack int32 (harness-normalized int8 values in [-127,127]) -> int8.
// One thread = one v4i load (16 B/lane) + one dword store. Known-good.
// ---------------------------------------------------------------------------
__device__ __forceinline__ int pack4(v4i v) {
    return (int)(((uint32_t)v.x & 0xffu)
               | (((uint32_t)v.y & 0xffu) << 8)
               | (((uint32_t)v.z & 0xffu) << 16)
               | (((uint32_t)v.w & 0xffu) << 24));
}

__global__ __launch_bounds__(256) void pack_ab(
    const int* __restrict__ srcA, const int* __restrict__ srcB,
    int* __restrict__ dstA, int* __restrict__ dstB,
    int aGroups)
{
    int g = blockIdx.x * 256 + threadIdx.x;
    const v4i* src;
    int* dst;
    if (g < aGroups) { src = (const v4i*)srcA; dst = dstA; }
    else             { src = (const v4i*)srcB; dst = dstB; g -= aGroups; }
    dst[g] = pack4(src[g]);
}

// ---------------------------------------------------------------------------
// Async global->LDS, 16B per lane (m104/m108 constraints).
// ---------------------------------------------------------------------------
__device__ __forceinline__ void gload16(const void* g, void* lds_p) {
    __builtin_amdgcn_global_load_lds(
        (__attribute__((address_space(1))) void*)(g),
        (__attribute__((address_space(3))) void*)(lds_p),
        16, 0, 0);
}

// 32-bit LDS byte address for inline-asm ds_read (same AS3 cast gload16 uses).
__device__ __forceinline__ uint32_t lds_addr32(void* p) {
    return (uint32_t)(uintptr_t)(__attribute__((address_space(3))) void*)p;
}

// Inline-asm ds_read_b128: base VGPR + compile-time 16-bit immediate offset.
// The compiler's SIWaitcnts pass does NOT track these destinations, so it
// inserts no conservative lgkm waits before the MFMA cluster -- WE place
// counted lgkmcnt(N) manually (rule #18: sched_barrier(0) must follow).
template<int IMM>
__device__ __forceinline__ v4i dsr(uint32_t base) {
    v4i d;
    asm volatile("ds_read_b128 %0, %1 offset:%2"
                 : "=v"(d) : "v"(base), "i"(IMM));
    return d;
}

// ---------------------------------------------------------------------------
// Phase 2, ROUND 7: geometry/schedule = R3 (256x256, BK=128, 8 waves, 8-phase,
// counted vmcnt(4), XOR swizzle (0 conflicts), setprio, XCD swizzle; verified
// absmax 2.4e-4). CHANGE: fragment reads are inline-asm ds_read_b128 with
// counted lgkmcnt(NRD) waits.
//
// Why: R2 == R3 == 1331 cyc/phase = MFMA(653) + LDS(576) SERIAL. R3's
// one-phase-ahead register pipeline should have overlapped them; the only
// mechanism that serializes no-data-dep streams is a waitcnt => hipcc's
// auto-inserted lgkm waits drained the new reads before each MFMA cluster.
// Fix (HK techniques 1+2, plain HIP): asm ds_reads (compiler stops tracking)
// + manual s_waitcnt lgkmcnt(NRD) where NRD = reads issued THIS phase, so
// the wait covers exactly last phase's reads (whose frags the MFMAs consume)
// while this phase's reads drain UNDER the MFMAs.
//
// Hazard audit: unchanged from R3 (stage->read distances, vmcnt(4) at p4/p8
// certifying buf1/buf0, >=3-phase WAR distances). lgkm accounting: per-wave
// DS ops complete in order; at LGKMW(NRD), outstanding = NRD (this phase) +
// residue(last phase); waiting to <=NRD forces residue=0 => frags certified.
// Only DS ops in flight are these asm reads (global_load_lds = vmcnt only;
// no flat/SMEM in the loop).
//
// LDS base+offset map: A(buf) base = lds + buf*65536 + wm*8192 + rd,
// imm = ksh*16384 + qm*4096 + k*1024 (max 23552 < 64K).  B(buf) base =
// lds + 32768 + buf*65536 + wn*4096 + rd, imm = ksh*16384 + k*1024.
// ---------------------------------------------------------------------------
__global__ __launch_bounds__(512, 2) void int8_gemm_dequant(
    const int8_t* __restrict__ A,        // [M,K] int8 packed
    const float*  __restrict__ scale_x,  // [M]
    const int8_t* __restrict__ W,        // [N,K] int8 packed
    const float*  __restrict__ scale_w,  // [N]
    const float*  __restrict__ bias,     // [N] (harness-normalized fp16->f32)
    float*        __restrict__ out)      // [M,N] f32
{
    __shared__ __align__(16) int8_t lds[131072];   // 128 KiB

    const int t    = threadIdx.x;          // 0..511
    const int lane = t & 63;
    const int w    = t >> 6;               // wave 0..7
    const int wm   = w >> 2;               // 0..1  (M half: 128 rows)
    const int wn   = w & 3;                // 0..3  (N quarter: 64 cols)

    // Bijective XCD swizzle (512 % 8 == 0).
    const int wg  = blockIdx.x;
    const int swz = (wg & 7) * 64 + (wg >> 3);
    const int n0  = (swz & 15) * 256;
    const int m0  = (swz >> 4) * 256;

    // Staging: thread t owns slots t and t+512 of each 16 KB region.
    // slot s -> row = s>>2, sc = s&3, global k-granule cg = sc ^ ((s>>3)&3).
    const int srow = t >> 2;                        // 0..127 (2nd load: +128)
    const int scg  = (t & 3) ^ ((t >> 3) & 3);      // same for slot t+512
    const int8_t* Ap = A + (size_t)(m0 + srow) * K_DIM + scg * 16;
    const int8_t* Bp = W + (size_t)(n0 + srow) * K_DIM + scg * 16;
    int8_t* ldsb = &lds[t * 16];

    // Fragment read: lane reads row (base + (lane&15)), k-granule cg=lane>>4;
    // swizzled col = cg ^ ((lane>>1)&3) (base rows are multiples of 16).
    const int rd = (lane & 15) * 64 + (((lane >> 4) ^ ((lane >> 1) & 3)) * 16);

    // Loop-invariant ds_read base registers (buf0/buf1 x A/B).
    const uint32_t bA0 = lds_addr32(&lds[wm * 8192 + rd]);
    const uint32_t bA1 = bA0 + 65536;
    const uint32_t bB0 = lds_addr32(&lds[32768 + wn * 4096 + rd]);
    const uint32_t bB1 = bB0 + 65536;

    v4i acc[8][4] = {};                    // [qm*4+mt][nt]
    v4i afr0[4], afr1[4], bfr0[4], bfr1[4];

#define HOFF(buf, mat, ksh) ((((buf) << 2) | ((mat) << 1) | (ksh)) << 14)

#define STAGE(buf, mat, ksh, OFF) do {                                        \
    const int8_t* _g = ((mat) ? Bp : Ap) + (OFF) + (ksh) * 64;                \
    int8_t* _d = ldsb + HOFF(buf, mat, ksh);                                  \
    gload16(_g, _d);                                                          \
    gload16(_g + (size_t)128 * K_DIM, _d + 8192);                             \
} while (0)

#define RD_A(DST, BASE, ksh, qm) do {                                         \
    DST[0] = dsr<(ksh) * 16384 + (qm) * 4096 +    0>(BASE);                   \
    DST[1] = dsr<(ksh) * 16384 + (qm) * 4096 + 1024>(BASE);                   \
    DST[2] = dsr<(ksh) * 16384 + (qm) * 4096 + 2048>(BASE);                   \
    DST[3] = dsr<(ksh) * 16384 + (qm) * 4096 + 3072>(BASE);                   \
} while (0)

#define RD_B(DST, BASE, ksh) do {                                             \
    DST[0] = dsr<(ksh) * 16384 +    0>(BASE);                                 \
    DST[1] = dsr<(ksh) * 16384 + 1024>(BASE);                                 \
    DST[2] = dsr<(ksh) * 16384 + 2048>(BASE);                                 \
    DST[3] = dsr<(ksh) * 16384 + 3072>(BASE);                                 \
} while (0)

#define MFMA_Q(qm, AF, BF) do {                                               \
    _Pragma("unroll")                                                         \
    for (int mt = 0; mt < 4; ++mt) {                                          \
        _Pragma("unroll")                                                     \
        for (int nt = 0; nt < 4; ++nt) {                                      \
            acc[(qm) * 4 + mt][nt] = __builtin_amdgcn_mfma_i32_16x16x64_i8(   \
                AF[mt], BF[nt], acc[(qm) * 4 + mt][nt], 0, 0, 0);             \
        }                                                                     \
    }                                                                         \
} while (0)

#define NOWAIT ((void)0)
#define WAIT4  asm volatile("s_waitcnt vmcnt(4)" ::: "memory")
#define WAIT0  asm volatile("s_waitcnt vmcnt(0)" ::: "memory")
#define NOSTG  ((void)0)
#define NORD   ((void)0)

// Counted lgkm wait + mandatory scheduling fence (rule #18).
#define LGKMW(N) do {                                                         \
    asm volatile("s_waitcnt lgkmcnt(%0)" :: "i"(N) : "memory");               \
    __builtin_amdgcn_sched_barrier(0);                                        \
} while (0)

// Phase: stage (vmem) -> [counted vmcnt] -> barrier -> fence -> issue NEXT
// phase's asm ds_reads -> lgkmcnt(NRD) (certifies LAST phase's reads only)
// -> MFMA current frags while this phase's reads drain underneath.
#define PH(qm, AF, BF, NEXTRD, NRD, STG, WAITV) do {                          \
    STG;                                                                      \
    WAITV;                                                                    \
    __builtin_amdgcn_s_barrier();                                             \
    __builtin_amdgcn_sched_barrier(0);                                        \
    NEXTRD;                                                                   \
    LGKMW(NRD);                                                               \
    __builtin_amdgcn_s_setprio(1);                                            \
    MFMA_Q(qm, AF, BF);                                                       \
    __builtin_amdgcn_s_setprio(0);                                            \
} while (0)

    // Prologue: tile0 full + tile1 ks0 staged; drain tile0, leave tile1.ks0's
    // 4 in flight (steady-state entry). Pre-read phase-1 fragments (8 reads;
    // first PH's LGKMW(4) certifies them).
    STAGE(0, 1, 0, 0);   STAGE(0, 0, 0, 0);
    STAGE(0, 1, 1, 0);   STAGE(0, 0, 1, 0);
    STAGE(1, 1, 0, 128); STAGE(1, 0, 0, 128);
    WAIT4;
    __builtin_amdgcn_s_barrier();
    __builtin_amdgcn_sched_barrier(0);
    RD_A(afr0, bA0, 0, 0);
    RD_B(bfr0, bB0, 0);

    // Main loop: i = 0..14; Ap/Bp advance 256 B/iter; stage offsets are
    // immediates: T1 = +128, T2 = +256, T3 = +384 (ksh adds 64).
    // Phase p computes (buf,ksh,qm); NEXTRD fetches p+1's frags.
    for (int i = 0; i < 15; ++i) {
        PH(0, afr0, bfr0, RD_A(afr1, bA0, 0, 1), 4,
           STAGE(1, 1, 1, 128), NOWAIT);                                // p1
        PH(1, afr1, bfr0,
           { RD_A(afr0, bA0, 1, 0); RD_B(bfr1, bB0, 1); }, 8,
           STAGE(1, 0, 1, 128), NOWAIT);                                // p2
        PH(0, afr0, bfr1, RD_A(afr1, bA0, 1, 1), 4,
           STAGE(0, 1, 0, 256), NOWAIT);                                // p3
        PH(1, afr1, bfr1,
           { RD_A(afr0, bA1, 0, 0); RD_B(bfr0, bB1, 0); }, 8,
           STAGE(0, 0, 0, 256), WAIT4);                                 // p4
        PH(0, afr0, bfr0, RD_A(afr1, bA1, 0, 1), 4,
           STAGE(0, 1, 1, 256), NOWAIT);                                // p5
        PH(1, afr1, bfr0,
           { RD_A(afr0, bA1, 1, 0); RD_B(bfr1, bB1, 1); }, 8,
           STAGE(0, 0, 1, 256), NOWAIT);                                // p6
        PH(0, afr0, bfr1, RD_A(afr1, bA1, 1, 1), 4,
           STAGE(1, 1, 0, 384), NOWAIT);                                // p7
        PH(1, afr1, bfr1,
           { RD_A(afr0, bA0, 0, 0); RD_B(bfr0, bB0, 0); }, 8,
           STAGE(1, 0, 0, 384), WAIT4);                                 // p8
        Ap += 256; Bp += 256;
    }

    // Peeled final iteration (tiles 30,31): finish staging tile31.ks1, full
    // vmcnt drain once (WAIT0 certifies T31 before p4's just-in-time reads).
    PH(0, afr0, bfr0, RD_A(afr1, bA0, 0, 1), 4, STAGE(1, 1, 1, 128), NOWAIT);
    PH(1, afr1, bfr0,
       { RD_A(afr0, bA0, 1, 0); RD_B(bfr1, bB0, 1); }, 8,
       STAGE(1, 0, 1, 128), NOWAIT);
    PH(0, afr0, bfr1, RD_A(afr1, bA0, 1, 1), 4, NOSTG, NOWAIT);
    PH(1, afr1, bfr1,
       { RD_A(afr0, bA1, 0, 0); RD_B(bfr0, bB1, 0); }, 8, NOSTG, WAIT0);
    PH(0, afr0, bfr0, RD_A(afr1, bA1, 0, 1), 4, NOSTG, NOWAIT);
    PH(1, afr1, bfr0,
       { RD_A(afr0, bA1, 1, 0); RD_B(bfr1, bB1, 1); }, 8, NOSTG, NOWAIT);
    PH(0, afr0, bfr1, RD_A(afr1, bA1, 1, 1), 4, NOSTG, NOWAIT);
    PH(1, afr1, bfr1, NORD, 0, NOSTG, NOWAIT);

    // Epilogue: dequant + bias. C/D layout (16x16, dtype-independent):
    // col = lane&15, row = (lane>>4)*4 + reg.
    const int col = lane & 15;
    const int rq  = (lane >> 4) * 4;
    const float inv127sq = 1.0f / (127.0f * 127.0f);
    const int mbase = m0 + wm * 128;
    const int nbase = n0 + wn * 64;

    float sx[8][4];
#pragma unroll
    for (int ii = 0; ii < 8; ++ii) {
        const int mrow = mbase + (ii >> 2) * 64 + (ii & 3) * 16 + rq;
#pragma unroll
        for (int r = 0; r < 4; ++r) sx[ii][r] = scale_x[mrow + r];
    }

#pragma unroll
    for (int j = 0; j < 4; ++j) {
        const int n  = nbase + j * 16 + col;
        const float sw = scale_w[n] * inv127sq;
        const float bf = bias[n];
#pragma unroll
        for (int ii = 0; ii < 8; ++ii) {
            const int mrow = mbase + (ii >> 2) * 64 + (ii & 3) * 16 + rq;
#pragma unroll
            for (int r = 0; r < 4; ++r) {
                out[(size_t)(mrow + r) * N_DIM + n] =
                    (float)acc[ii][j][r] * sx[ii][r] * sw + bf;
            }
        }
    }

#undef HOFF
#undef STAGE
#undef RD_A
#undef RD_B
#undef MFMA_Q
#undef NOWAIT
#undef WAIT4
#undef WAIT0
#undef NOSTG
#undef NORD
#undef LGKMW
#undef PH
}

extern "C" void kernel_launch(void* const* d_in, const int* in_sizes, int n_in,
                              void* d_out, int out_size, void* d_ws, size_t ws_size,
                              hipStream_t stream) {
    // Harness normalization: integer inputs -> int32, fp16 -> f32.
    const int*   x_i32   = (const int*)  d_in[0];   // [M,K] as int32
    const float* scale_x = (const float*)d_in[1];   // [M] f32
    const int*   w_i32   = (const int*)  d_in[2];   // [N,K] as int32
    const float* scale_w = (const float*)d_in[3];   // [N] f32
    const float* bias    = (const float*)d_in[4];   // [N] f32 (from fp16)
    float* out = (float*)d_out;                     // [M,N] f32

    // Scratch layout: packed A8 then B8.
    int8_t* A8 = (int8_t*)d_ws;                          // 33,554,432 B
    int8_t* B8 = A8 + (size_t)M_DIM * K_DIM;             // 16,777,216 B

    const int a_groups = (M_DIM * K_DIM) / 4;            // 8,388,608
    const int b_groups = (N_DIM * K_DIM) / 4;            // 4,194,304
    const int total    = a_groups + b_groups;            // 12,582,912 (÷256)
    pack_ab<<<total / 256, 256, 0, stream>>>(x_i32, w_i32, (int*)A8, (int*)B8,
                                             a_groups);

    // 256x256 tiles: grid = (8192/256)*(4096/256) = 32*16 = 512 blocks.
    int8_gemm_dequant<<<512, 512, 0, stream>>>(A8, scale_x, B8, scale_w, bias, out);
}